// Round 18
// baseline (117.733 us; speedup 1.0000x reference)
//
#include <hip/hip_runtime.h>

namespace {
constexpr int kB    = 8;
constexpr int kC    = 64;
constexpr int kH    = 64, kW = 64;
constexpr int kNP   = 8192;             // positions
constexpr int kC1In = 1092;
constexpr int kKP   = 1152;             // padded K for GEMM1 (18 x 64)
constexpr int kC1Out= 313;
constexpr int kC2Out= 3136;
constexpr int kC1P  = 320;              // padded C1Out
constexpr int kRowS = 56;               // fp16/bf16 per (pos,n) row: 49 + 7 zero pad
constexpr int kPosS = 16 * kRowS + 8;   // 904 per pos
// merged pre-kernel block ranges
constexpr int kPreFeat = 2048;          // 4 g x 512 ptiles
constexpr int kPreW2   = 490;           // 125440 / 256
constexpr int kPreW1   = 1440;          // 368640 / 256
constexpr int kPreBlocks = kPreFeat + kPreW2 + kPreW1;   // 3978
// phase-4 x-stage dims (bf16): [16ch][7rows][70cols], col index = xx+3
constexpr int kXlsC = 70;
constexpr int kXlsCh = 7 * kXlsC;       // 490
}

typedef __attribute__((ext_vector_type(8))) short bf16x8;
typedef __attribute__((ext_vector_type(8))) _Float16 f16x8;
typedef __attribute__((ext_vector_type(4))) float f32x4;

__device__ __forceinline__ unsigned short f2bf(float f) {
    unsigned u = __float_as_uint(f);
    unsigned r = (u + 0x7fffu + ((u >> 16) & 1u)) >> 16;   // RNE
    return (unsigned short)r;
}
__device__ __forceinline__ float bf2f(unsigned short h) {
    return __uint_as_float(((unsigned)h) << 16);
}

// ---------------- K_pre: feat | w2split | w1cvt(+stat zero) by block range --
__global__ __launch_bounds__(256) void k_pre(const float* __restrict__ x,
        const float* __restrict__ w1, const float* __restrict__ w2,
        unsigned short* __restrict__ feat_bf, unsigned short* __restrict__ w1s,
        bf16x8* __restrict__ w2t, float* __restrict__ stats) {
    __shared__ float xs[16 * 7 * 40];   // 11.2 KB (feat branch only)
    int tid = threadIdx.x;
    int bid = blockIdx.x;

    if (bid < kPreFeat) {               // ---- feat ----
        int g = bid >> 9, pt = bid & 511;
        int p0 = pt * 16;
        int b = p0 >> 10, i = (p0 >> 5) & 31, j0 = p0 & 31;
        int y0 = 2 * i - 3, xbase = 2 * j0 - 3;
        const float* xb = x + ((size_t)(b * 64 + g * 16) << 12);

        for (int idx = tid; idx < 16 * 7 * 40; idx += 256) {
            int ch = idx / 280, r2 = idx - ch * 280;
            int row = r2 / 40, col = r2 - row * 40;
            int yy = y0 + row, xx = xbase + col;
            float v = 0.f;
            if ((unsigned)yy < 64u && (unsigned)xx < 64u)
                v = xb[(ch << 12) + (yy << 6) + xx];
            xs[idx] = v;
        }
        __syncthreads();

        for (int pos = 0; pos < 16; ++pos) {
            for (int c = tid; c < 273; c += 256) {
                float m = -INFINITY;
                int cg;
                if (c < 49) {
                    int a = c / 7, bk = c - a * 7;
                    int base = a * 40 + 2 * pos + bk;
                    #pragma unroll
                    for (int ch = 0; ch < 16; ++ch) m = fmaxf(m, xs[ch * 280 + base]);
                    cg = g * 49 + c;
                } else if (c < 161) {
                    int r = c - 49;
                    int ch = r / 7, bk = r - ch * 7;
                    int base = ch * 280 + 2 * pos + bk;
                    #pragma unroll
                    for (int a = 0; a < 7; ++a) m = fmaxf(m, xs[base + a * 40]);
                    cg = 196 + g * 112 + r;
                } else {
                    int r = c - 161;
                    int ch = r / 7, a = r - ch * 7;
                    int base = ch * 280 + a * 40 + 2 * pos;
                    #pragma unroll
                    for (int bk = 0; bk < 7; ++bk) m = fmaxf(m, xs[base + bk]);
                    cg = 644 + g * 112 + r;
                }
                feat_bf[(size_t)(p0 + pos) * kKP + cg] = f2bf(m);
            }
        }
        if (g == 3) {   // zero-fill K-pad [1092,1152)
            for (int idx = tid; idx < 16 * 60; idx += 256) {
                int pos = idx / 60, c = idx - pos * 60;
                feat_bf[(size_t)(p0 + pos) * kKP + 1092 + c] = 0;
            }
        }
    } else if (bid < kPreFeat + kPreW2) {   // ---- w2split (16x16 frag layout) ----
        int idx = (bid - kPreFeat) * 256 + tid;   // < 125440
        int lane = idx & 63;
        int t = (idx >> 6) % 10;
        int k = (idx / 640) % 49;
        int g = idx / 31360;
        int n = lane & 15, c0 = t * 32 + ((lane >> 4) << 3);
        int row = g * 784 + k * 16 + n;
        bf16x8 hi;
        #pragma unroll
        for (int e = 0; e < 8; ++e) {
            int c = c0 + e;
            float v = (c < kC1Out) ? w2[(size_t)row * kC1Out + c] : 0.f;
            hi[e] = (short)f2bf(v);
        }
        w2t[idx] = hi;
    } else {                                 // ---- w1cvt + stat zero ----
        int idx = (bid - kPreFeat - kPreW2) * 256 + tid;   // < 368640
        if (idx < 640) stats[idx] = 0.f;
        int r = idx / kKP, c = idx - r * kKP;
        float v = (r < kC1Out && c < kC1In) ? w1[(size_t)r * kC1In + c] : 0.f;
        w1s[idx] = f2bf(v);
    }
}

// ---------------- K2: MFMA GEMM1, BM=128 BN=64 BK=64, 8 waves (4x2) --------
__global__ __launch_bounds__(512) void k_gemm1(
        const unsigned short* __restrict__ feat_bf, const unsigned short* __restrict__ w1s,
        unsigned short* __restrict__ hb16, float* __restrict__ sum_, float* __restrict__ sumsq_) {
    __shared__ unsigned short Ald[128 * 64];   // 16 KB
    __shared__ unsigned short Bld[64 * 64];    // 8 KB
    __shared__ float lsum[64], lsq[64];
    int tid = threadIdx.x;
    int lane = tid & 63, wv = tid >> 6;        // wv 0..7
    int row0 = blockIdx.x * 128, col0 = blockIdx.y * 64;
    int wr = wv >> 1, wc = wv & 1;             // 4 x 2 wave grid
    int srow = lane >> 3;
    int soct = (lane & 7) ^ srow;
    int frow = lane & 15, fk = lane >> 4;

    f32x4 acc[2][2] = {};
    for (int k0 = 0; k0 < kKP; k0 += 64) {
        #pragma unroll
        for (int qq = 0; qq < 3; ++qq) {       // 24 chunks: 16 A + 8 B
            int q = wv + qq * 8;
            const unsigned short* srcbase;
            unsigned short* dst;
            int grow;
            if (q < 16) { grow = row0 + q * 8 + srow; srcbase = feat_bf; dst = Ald + q * 512; }
            else        { grow = col0 + (q - 16) * 8 + srow; srcbase = w1s; dst = Bld + (q - 16) * 512; }
            const unsigned short* src = srcbase + (size_t)grow * kKP + k0 + soct * 8;
            __builtin_amdgcn_global_load_lds(
                (const __attribute__((address_space(1))) unsigned int*)src,
                (__attribute__((address_space(3))) unsigned int*)dst, 16, 0, 0);
        }
        __syncthreads();
        #pragma unroll
        for (int ks = 0; ks < 2; ++ks) {
            int oct = ks * 4 + fk;
            bf16x8 a0, a1, b0, b1;
            { int r = wr * 32 + frow;      a0 = *(const bf16x8*)(Ald + (r * 8 + (oct ^ (r & 7))) * 8); }
            { int r = wr * 32 + 16 + frow; a1 = *(const bf16x8*)(Ald + (r * 8 + (oct ^ (r & 7))) * 8); }
            { int r = wc * 32 + frow;      b0 = *(const bf16x8*)(Bld + (r * 8 + (oct ^ (r & 7))) * 8); }
            { int r = wc * 32 + 16 + frow; b1 = *(const bf16x8*)(Bld + (r * 8 + (oct ^ (r & 7))) * 8); }
            acc[0][0] = __builtin_amdgcn_mfma_f32_16x16x32_bf16(a0, b0, acc[0][0], 0, 0, 0);
            acc[0][1] = __builtin_amdgcn_mfma_f32_16x16x32_bf16(a0, b1, acc[0][1], 0, 0, 0);
            acc[1][0] = __builtin_amdgcn_mfma_f32_16x16x32_bf16(a1, b0, acc[1][0], 0, 0, 0);
            acc[1][1] = __builtin_amdgcn_mfma_f32_16x16x32_bf16(a1, b1, acc[1][1], 0, 0, 0);
        }
        __syncthreads();
    }

    if (tid < 64) { lsum[tid] = 0.f; lsq[tid] = 0.f; }
    __syncthreads();
    #pragma unroll
    for (int j = 0; j < 2; ++j) {
        int col_l = wc * 32 + j * 16 + (lane & 15);
        float s = 0.f, sq = 0.f;
        #pragma unroll
        for (int i = 0; i < 2; ++i) {
            int mrow = row0 + wr * 32 + i * 16 + (lane >> 4) * 4;
            #pragma unroll
            for (int r = 0; r < 4; ++r) {
                float v = acc[i][j][r];
                hb16[(size_t)(mrow + r) * kC1P + col0 + col_l] = f2bf(v);
                s += v; sq += v * v;
            }
        }
        s  += __shfl_xor(s, 16);  s  += __shfl_xor(s, 32);
        sq += __shfl_xor(sq, 16); sq += __shfl_xor(sq, 32);
        if (lane < 16) {
            atomicAdd(&lsum[col_l], s);
            atomicAdd(&lsq[col_l], sq);
        }
    }
    __syncthreads();
    if (tid < 64 && col0 + tid < kC1Out) {
        atomicAdd(&sum_[col0 + tid], lsum[tid]);
        atomicAdd(&sumsq_[col0 + tid], lsq[tid]);
    }
}

// ---------------- K4a: BN(inline finalize)+ReLU hb16 -> frag-ready bf16 ----
__global__ void k_split_h(const unsigned short* __restrict__ hb16,
                          const float* __restrict__ sum_, const float* __restrict__ sumsq_,
                          const float* __restrict__ gamma, const float* __restrict__ beta,
                          bf16x8* __restrict__ ht_hi) {
    int idx = blockIdx.x * 256 + threadIdx.x;   // 512*10*64 = 327680
    int lane = idx & 63;
    int t = (idx >> 6) % 10;
    int ptile = idx / 640;
    int pos = ptile * 16 + (lane & 15);
    int c0 = t * 32 + ((lane >> 4) << 3);
    bf16x8 raw = *(const bf16x8*)(hb16 + (size_t)pos * kC1P + c0);
    bf16x8 hi;
    #pragma unroll
    for (int e = 0; e < 8; ++e) {
        int c = c0 + e;
        float v = 0.f;
        if (c < kC1Out) {
            float mu  = sum_[c]   * (1.f / kNP);
            float var = sumsq_[c] * (1.f / kNP) - mu * mu;
            float sc  = gamma[c] * rsqrtf(var + 1e-5f);
            float sh  = beta[c] - mu * sc;
            v = fmaxf(bf2f((unsigned short)raw[e]) * sc + sh, 0.f);
        }
        hi[e] = (short)f2bf(v);
    }
    ht_hi[idx] = hi;
}

// ---------------- K4b: pair-slot MFMA GEMM2 -> softmax(49) -> MFMA phase 4 --
// GEMM + softmax identical to the 59.6us round-13 form, except softmax now
// writes layout-B rows as BF16. Phase 4 rewritten as MFMA: per pos,
// out[c16][n] = patch(16x64) x e(16x64)^T via 2x mfma_16x16x32_bf16.
// Kills the 112-b128/thread e-read storm (16x redundancy) and the 448-deep
// fdot2 chains; x gathered once, coalesced, into xls (htl's dead space).
__global__ __launch_bounds__(512) void k_fused(
        const bf16x8* __restrict__ ht_hi, const bf16x8* __restrict__ w2t,
        const float* __restrict__ b2, const float* __restrict__ x,
        float* __restrict__ out) {
    __shared__ _Float16 wtb[32 * kPosS];   // 57,856 B
    __shared__ float invt[512];            // 2,048 B
    __shared__ bf16x8 htl[1280];           // 20,480 B -> total 80,384 B
    int tid = threadIdx.x;
    int lane = tid & 63, wv = tid >> 6;
    int bid = blockIdx.x;
    int g = bid >> 8, pt = bid & 255;      // 32-position tile pt
    int bb = pt >> 5, ii = pt & 31;        // all pos share (b, i); j = pos
    int y0 = 2 * ii - 3;

    // stage ht (both 16-pos halves) linearly into LDS
    {
        const bf16x8* hb = ht_hi + (size_t)(pt * 2) * 640;
        #pragma unroll
        for (int r = 0; r < 3; ++r) {
            int idx = r * 512 + tid;
            if (idx < 1280)
                __builtin_amdgcn_global_load_lds(
                    (const __attribute__((address_space(1))) unsigned int*)(hb + idx),
                    (__attribute__((address_space(3))) unsigned int*)(htl + idx), 16, 0, 0);
        }
    }
    __syncthreads();

    int col = lane & 15, rgrp = lane >> 4;
    for (int k = wv; k < 49; k += 16) {
        int k2 = k + 8;
        bool has2 = (k2 < 49);
        int k2c = has2 ? k2 : k;           // clamp: duplicate work, discarded
        f32x4 acc00 = {0.f,0.f,0.f,0.f}, acc01 = {0.f,0.f,0.f,0.f};
        f32x4 acc10 = {0.f,0.f,0.f,0.f}, acc11 = {0.f,0.f,0.f,0.f};
        const bf16x8* wb0 = w2t + ((size_t)(g * 49 + k)   * 10) * 64 + lane;
        const bf16x8* wb1 = w2t + ((size_t)(g * 49 + k2c) * 10) * 64 + lane;
        bf16x8 bh0[10], bh1[10];
        #pragma unroll
        for (int t = 0; t < 10; ++t) { bh0[t] = wb0[t * 64]; bh1[t] = wb1[t * 64]; }
        #pragma unroll
        for (int t = 0; t < 10; ++t) {
            bf16x8 a0 = htl[t * 64 + lane];
            bf16x8 a1 = htl[640 + t * 64 + lane];
            acc00 = __builtin_amdgcn_mfma_f32_16x16x32_bf16(a0, bh0[t], acc00, 0, 0, 0);
            acc01 = __builtin_amdgcn_mfma_f32_16x16x32_bf16(a1, bh0[t], acc01, 0, 0, 0);
            acc10 = __builtin_amdgcn_mfma_f32_16x16x32_bf16(a0, bh1[t], acc10, 0, 0, 0);
            acc11 = __builtin_amdgcn_mfma_f32_16x16x32_bf16(a1, bh1[t], acc11, 0, 0, 0);
        }
        {
            float bias = b2[g * 784 + k * 16 + col];
            #pragma unroll
            for (int r = 0; r < 4; ++r) {
                int pos = rgrp * 4 + r;        // C: row=(lane>>4)*4+reg
                wtb[pos * kPosS + k * 16 + col]        = (_Float16)(acc00[r] + bias);
                wtb[(pos + 16) * kPosS + k * 16 + col] = (_Float16)(acc01[r] + bias);
            }
        }
        if (has2) {
            float bias = b2[g * 784 + k2 * 16 + col];
            #pragma unroll
            for (int r = 0; r < 4; ++r) {
                int pos = rgrp * 4 + r;
                wtb[pos * kPosS + k2 * 16 + col]        = (_Float16)(acc10[r] + bias);
                wtb[(pos + 16) * kPosS + k2 * 16 + col] = (_Float16)(acc11[r] + bias);
            }
        }
    }
    __syncthreads();

    // ---- x-stage (htl is dead now): xls[16ch][7][70] bf16, coalesced ----
    unsigned short* xls = (unsigned short*)htl;
    {
        const float* xg = x + (((size_t)bb * 64 + g * 16) << 12);
        for (int idx = tid; idx < 16 * kXlsCh; idx += 512) {
            int ch = idx / kXlsCh, r2 = idx - ch * kXlsCh;
            int a = r2 / kXlsC, cc = r2 - a * kXlsC;
            int yy = y0 + a, xx = cc - 3;
            float v = 0.f;
            if ((unsigned)yy < 64u && (unsigned)xx < 64u)
                v = xg[(ch << 12) + (yy << 6) + xx];
            xls[idx] = f2bf(v);
        }
    }

    // softmax per (pos, n): read layout A -> regs -> barrier -> write layout B (bf16)
    {
        int pos = tid >> 4, n = tid & 15;
        const _Float16* baseA = wtb + pos * kPosS + n;
        float vv[49];
        float m = -INFINITY;
        #pragma unroll
        for (int k = 0; k < 49; ++k) {
            float v = (float)baseA[k * 16];
            vv[k] = v;
            m = fmaxf(m, v);
        }
        float s = 0.f;
        #pragma unroll
        for (int k = 0; k < 49; ++k) {
            float ex = __expf(vv[k] - m);
            s += ex;
            vv[k] = ex;
        }
        __syncthreads();                           // all A-reads done before B-writes
        unsigned short* baseB = (unsigned short*)(wtb + pos * kPosS + n * kRowS);
        #pragma unroll
        for (int c = 0; c < 7; ++c) {
            bf16x8 sb;
            #pragma unroll
            for (int e = 0; e < 8; ++e) {
                int k = c * 8 + e;
                sb[e] = (k < 49) ? (short)f2bf(vv[k]) : (short)0;
            }
            *(bf16x8*)(baseB + c * 8) = sb;
        }
        invt[tid] = 1.f / (s * 49.f);
    }
    __syncthreads();

    // ---- phase 4 as MFMA: per pos, out[c16][n] = patch x e^T (K=64) ----
    {
        int nidx = lane & 15, oct = lane >> 4;     // A row / B col = lane&15
        float* outg = out + (((size_t)bb * 64 + g * 16) << 14);
        #pragma unroll
        for (int pp = 0; pp < 4; ++pp) {
            int pos = wv * 4 + pp;                 // j = pos
            const unsigned short* xrow = xls + nidx * kXlsCh;   // c16 = nidx for A
            // A fragments: patch[c16][k], k = half*32 + oct*8 + e
            bf16x8 a0, a1;
            #pragma unroll
            for (int e = 0; e < 8; ++e) {
                int k = oct * 8 + e;               // 0..31, always < 49
                int a = k / 7, bk = k - a * 7;
                a0[e] = (short)xrow[a * kXlsC + 2 * pos + bk];
                int kk = 32 + oct * 8 + e;         // 32..63
                short v = 0;
                if (kk < 49) {
                    int a2 = kk / 7, bk2 = kk - a2 * 7;
                    v = (short)xrow[a2 * kXlsC + 2 * pos + bk2];
                }
                a1[e] = v;
            }
            // B fragments: e[n][k] rows (bf16, layout B), aligned b128
            const unsigned short* erow = (const unsigned short*)(wtb + pos * kPosS + nidx * kRowS);
            bf16x8 b0 = *(const bf16x8*)(erow + oct * 8);
            bf16x8 b1 = *(const bf16x8*)(erow + 32 + oct * 8);
            if (oct == 3) b1 = (bf16x8){0,0,0,0,0,0,0,0};   // k 56..63
            f32x4 acc = {0.f, 0.f, 0.f, 0.f};
            acc = __builtin_amdgcn_mfma_f32_16x16x32_bf16(a0, b0, acc, 0, 0, 0);
            acc = __builtin_amdgcn_mfma_f32_16x16x32_bf16(a1, b1, acc, 0, 0, 0);
            // C: col = lane&15 = n, row = oct*4 + r = c16
            float scv = invt[pos * 16 + nidx];
            int n1 = nidx >> 2, n2 = nidx & 3;
            float* outp = outg + (ii * 4 + n1) * 128 + pos * 4 + n2;
            #pragma unroll
            for (int r = 0; r < 4; ++r) {
                int c16 = oct * 4 + r;
                outp[(size_t)c16 << 14] = acc[r] * scv;
            }
        }
    }
}

extern "C" void kernel_launch(void* const* d_in, const int* in_sizes, int n_in,
                              void* d_out, int out_size, void* d_ws, size_t ws_size,
                              hipStream_t stream) {
    const float* x     = (const float*)d_in[0];
    const float* w1    = (const float*)d_in[1];
    const float* gamma = (const float*)d_in[2];
    const float* beta  = (const float*)d_in[3];
    const float* w2    = (const float*)d_in[4];
    const float* b2    = (const float*)d_in[5];
    float* out = (float*)d_out;

    float* ws = (float*)d_ws;
    unsigned short* feat_bf = (unsigned short*)ws;            // 4,718,592 fl-equiv
    unsigned short* hb16 = (unsigned short*)(ws + 4718592);   // 8192*320 us = 1,310,720 fl
    float* w2t_f   = ws + 4718592 + 1310720;                  // 501,760 fl
    unsigned short* w1s = (unsigned short*)(w2t_f + 501760);  // 184,320 fl
    float* sum_   = w2t_f + 501760 + 184320;
    float* sumsq_ = sum_ + 320;

    bf16x8* ht_hi = (bf16x8*)ws;                              // reuses feat region
    bf16x8* w2t   = (bf16x8*)w2t_f;

    k_pre<<<kPreBlocks, 256, 0, stream>>>(x, w1, w2, feat_bf, w1s, w2t, sum_);
    k_gemm1<<<dim3(kNP / 128, 5), 512, 0, stream>>>(feat_bf, w1s, hb16, sum_, sumsq_);
    k_split_h<<<1280, 256, 0, stream>>>(hb16, sum_, sumsq_, gamma, beta, ht_hi);
    k_fused<<<1024, 512, 0, stream>>>(ht_hi, w2t, b2, x, out);
}